// Round 5
// baseline (126.906 us; speedup 1.0000x reference)
//
#include <hip/hip_runtime.h>

#define B_    4
#define N_    512
#define IND_  300
#define H_    128
#define QQ    8          // queries per attention block (even: paired for pk ops)
#define KC    4          // k-chunks (r5: 8->4 halves accum traffic + fin3 work,
                         // keeps 1024 blocks = 2 waves/SIMD)
#define RPB   4          // rows per prep block (2 per 128-thread group)
#define LOG2E 1.4426950408889634f

typedef float v2f __attribute__((ext_vector_type(2)));

// exp(x) deg-5 Taylor about c=-0.5 for x in [-1,0]; coeffs e^-0.5/k!.
// max err ~1.3e-5 on [-1,0]; all-positive coeffs keep p >= e for e>1 so
// med3(1,e,p) still selects e there.
#define EA0 0.60653065971263342f
#define EA1 0.60653065971263342f
#define EA2 0.30326532985631671f
#define EA3 0.10108844328543890f
#define EA4 0.02527211082135973f
#define EA5 0.00505442216427195f

// ---------------------------------------------------------------------------
// One fused packing kernel: transpose weights to [i/4][t][4] float4 tiles so
// prep's weight loads are coalesced dwordx4. Wa/Ua pre-scaled by log2e so
// prep can use raw exp2.
// ---------------------------------------------------------------------------
__global__ void pack_all(const float* __restrict__ Wx_w,
                         const float* __restrict__ Wa_w,
                         const float* __restrict__ Ua_w,
                         float* __restrict__ WxT4,
                         float* __restrict__ WaT4,
                         float* __restrict__ UaT4) {
    const int blk = blockIdx.x;
    const int t   = threadIdx.x;
    if (blk < IND_) {
        const int i = blk;
        WxT4[(i >> 2) * 512 + t * 4 + (i & 3)] = Wx_w[t * IND_ + i];
    } else if (blk < IND_ + H_) {
        const int i = blk - IND_;
        WaT4[(i >> 2) * 512 + t * 4 + (i & 3)] = Wa_w[t * H_ + i] * LOG2E;
    } else {
        const int i = blk - IND_ - H_;
        UaT4[(i >> 2) * 512 + t * 4 + (i & 3)] = Ua_w[t * H_ + i] * LOG2E;
    }
}

// ---------------------------------------------------------------------------
// Prep, RPB=4 via 256-thread blocks: two 128-thread groups per block, each
// owning 2 rows; both groups share the weight stream (L1 hits). 512 blocks
// = 2 waves/SIMD. (r3: traffic cut beyond RPB=2 is ~neutral — prep3 is at
// its latency/VALU floor; do not touch further.)
// ---------------------------------------------------------------------------
__global__ __launch_bounds__(256) void prep3(
    const float* __restrict__ x,      // [B*N, IND]
    const float* __restrict__ WxT4,   // packed [75][128][4]
    const float* __restrict__ Wx_b,
    const float* __restrict__ WaT4,   // packed [32][128][4], pre-scaled log2e
    const float* __restrict__ Wa_b,
    const float* __restrict__ UaT4,   // packed [32][128][4], pre-scaled log2e
    const float* __restrict__ Ua_b,
    const float* __restrict__ mask,   // [B*N, H]
    float* __restrict__ Eta,          // [B*N, H]
    float4* __restrict__ kv)          // [B*N, H] {Et, M, M*h, 0}
{
    __shared__ __align__(16) float xs[RPB][304];   // 304*4B row stride, 16B aligned
    __shared__ __align__(16) float hs[RPB][H_];

    const int r0 = blockIdx.x * RPB;
    const int t  = threadIdx.x;
    const int g  = t >> 7;            // group 0/1
    const int tt = t & 127;           // h index within group
    const int lr = 2 * g;             // group's first local row

    // all 256 threads cooperatively stage the 4 input rows
    #pragma unroll
    for (int rr = 0; rr < RPB; ++rr) {
        const float* xrow = x + (size_t)(r0 + rr) * IND_;
        for (int i = t; i < IND_; i += 256) xs[rr][i] = xrow[i];
    }
    __syncthreads();

    const float4* w4 = (const float4*)WxT4 + tt;
    const float bx = Wx_b[tt];
    float acc[2];
    acc[0] = bx;
    acc[1] = bx;

    #pragma unroll 5
    for (int i4 = 0; i4 < IND_ / 4; ++i4) {
        float4 w = w4[i4 * 128];      // identical stream in both groups -> L1 hit
        #pragma unroll
        for (int rr = 0; rr < 2; ++rr) {
            float4 xv = *(const float4*)(&xs[lr + rr][4 * i4]);  // lane-broadcast
            acc[rr] = fmaf(w.x, xv.x, acc[rr]);
            acc[rr] = fmaf(w.y, xv.y, acc[rr]);
            acc[rr] = fmaf(w.z, xv.z, acc[rr]);
            acc[rr] = fmaf(w.w, xv.w, acc[rr]);
        }
    }
    float hr[2];
    #pragma unroll
    for (int rr = 0; rr < 2; ++rr) {
        hr[rr] = tanhf(acc[rr]);
        hs[lr + rr][tt] = hr[rr];
    }
    __syncthreads();

    const float4* wa4 = (const float4*)WaT4 + tt;
    const float4* ua4 = (const float4*)UaT4 + tt;
    const float ba = Wa_b[tt] * LOG2E;
    const float bu = Ua_b[tt] * LOG2E;
    float accA[2], accU[2];
    accA[0] = ba; accA[1] = ba;
    accU[0] = bu; accU[1] = bu;

    #pragma unroll 4
    for (int i4 = 0; i4 < H_ / 4; ++i4) {
        float4 wa = wa4[i4 * 128];    // shared stream -> L1 hit for 2nd group
        float4 ua = ua4[i4 * 128];
        #pragma unroll
        for (int rr = 0; rr < 2; ++rr) {
            float4 hv = *(const float4*)(&hs[lr + rr][4 * i4]);
            accA[rr] = fmaf(wa.x, hv.x, accA[rr]);
            accA[rr] = fmaf(wa.y, hv.y, accA[rr]);
            accA[rr] = fmaf(wa.z, hv.z, accA[rr]);
            accA[rr] = fmaf(wa.w, hv.w, accA[rr]);
            accU[rr] = fmaf(ua.x, hv.x, accU[rr]);
            accU[rr] = fmaf(ua.y, hv.y, accU[rr]);
            accU[rr] = fmaf(ua.z, hv.z, accU[rr]);
            accU[rr] = fmaf(ua.w, hv.w, accU[rr]);
        }
    }

    #pragma unroll
    for (int rr = 0; rr < 2; ++rr) {
        const size_t o = (size_t)(r0 + lr + rr) * H_ + tt;
        Eta[o] = __builtin_amdgcn_exp2f(accA[rr]);
        float M = __builtin_amdgcn_exp2f(mask[o] * LOG2E);
        kv[o]  = make_float4(__builtin_amdgcn_exp2f(accU[rr]), M, M * hr[rr], 0.f);
    }
}

// ---------------------------------------------------------------------------
// Attention inner loop, packed-f32 + poly (no transcendentals):
//   e2  = eta2 * Et                        (v_pk_mul_f32)
//   u2  = e2 - 0.5                         (v_pk_add_f32)
//   p   = Taylor5(u2)  ~= exp(e-1)         (5x v_pk_fma_f32, err <= 1.3e-5)
//   p0  = med3(1, e, p)                    (v_med3_f32; == (e>1)?e:exp(e-1))
//   l2  += p0 * M                          (v_pk_fma_f32)
//   cc2 += p0 * (M*hv)                     (v_pk_fma_f32)
// Per 2 scores: 9 pk (18cy) + 2 med3 (4cy) = 22 cyc vs 28 with hw exp2.
// ---------------------------------------------------------------------------
__global__ __launch_bounds__(128) void attn3(
    const float* __restrict__ Eta,    // [B*N, H]
    const float4* __restrict__ kv,    // [B*N, H] {Et, M, M*hv, 0}
    float2* __restrict__ accum)       // [KC, B*N, H] {l, c}
{
    const int c  = blockIdx.x;        // 0..KC-1
    const int qg = blockIdx.y;        // 0..N/QQ-1
    const int b  = blockIdx.z;        // 0..B-1
    const int h  = threadIdx.x;
    const int q0 = qg * QQ;
    const int k0 = c * (N_ / KC);

    v2f eta2[QQ / 2], l2[QQ / 2], cc2[QQ / 2];
    #pragma unroll
    for (int j = 0; j < QQ / 2; ++j) {
        eta2[j][0] = Eta[((size_t)(b * N_ + q0 + 2 * j)) * H_ + h];
        eta2[j][1] = Eta[((size_t)(b * N_ + q0 + 2 * j + 1)) * H_ + h];
        l2[j][0] = 0.f;  l2[j][1] = 0.f;
        cc2[j][0] = 0.f; cc2[j][1] = 0.f;
    }

    // loop-invariant poly constants (VGPR pairs; VOP3P can't take literals)
    v2f cmH; cmH[0] = -0.5f; cmH[1] = -0.5f;
    v2f c5;  c5[0]  = EA5;   c5[1]  = EA5;
    v2f c4;  c4[0]  = EA4;   c4[1]  = EA4;
    v2f c3;  c3[0]  = EA3;   c3[1]  = EA3;
    v2f c2;  c2[0]  = EA2;   c2[1]  = EA2;
    v2f c1;  c1[0]  = EA1;   c1[1]  = EA1;
    v2f c0;  c0[0]  = EA0;   c0[1]  = EA0;

    const float4* kp = kv + ((size_t)(b * N_ + k0)) * H_ + h;

    #pragma unroll 4
    for (int k = 0; k < N_ / KC; ++k) {
        float4 v = kp[(size_t)k * H_];          // {Et, M, M*hv, 0}
        v2f vx; vx[0] = v.x; vx[1] = v.x;
        v2f vy; vy[0] = v.y; vy[1] = v.y;
        v2f vz; vz[0] = v.z; vz[1] = v.z;
        #pragma unroll
        for (int j = 0; j < QQ / 2; ++j) {
            v2f e2, u2, p;
            asm("v_pk_mul_f32 %0, %1, %2"
                : "=v"(e2) : "v"(eta2[j]), "v"(vx));
            asm("v_pk_add_f32 %0, %1, %2"
                : "=v"(u2) : "v"(e2), "v"(cmH));
            asm("v_pk_fma_f32 %0, %1, %2, %3"
                : "=v"(p) : "v"(u2), "v"(c5), "v"(c4));
            asm("v_pk_fma_f32 %0, %1, %2, %3"
                : "=v"(p) : "v"(p), "v"(u2), "v"(c3));
            asm("v_pk_fma_f32 %0, %1, %2, %3"
                : "=v"(p) : "v"(p), "v"(u2), "v"(c2));
            asm("v_pk_fma_f32 %0, %1, %2, %3"
                : "=v"(p) : "v"(p), "v"(u2), "v"(c1));
            asm("v_pk_fma_f32 %0, %1, %2, %3"
                : "=v"(p) : "v"(p), "v"(u2), "v"(c0));
            v2f p0;
            p0[0] = __builtin_amdgcn_fmed3f(1.0f, e2[0], p[0]);
            p0[1] = __builtin_amdgcn_fmed3f(1.0f, e2[1], p[1]);
            asm("v_pk_fma_f32 %0, %1, %2, %0"
                : "+v"(l2[j]) : "v"(p0), "v"(vy));
            asm("v_pk_fma_f32 %0, %1, %2, %0"
                : "+v"(cc2[j]) : "v"(p0), "v"(vz));
        }
    }

    #pragma unroll
    for (int j = 0; j < QQ / 2; ++j) {
        accum[((size_t)c * (B_ * N_) + b * N_ + q0 + 2 * j) * H_ + h] =
            make_float2(l2[j][0], cc2[j][0]);
        accum[((size_t)c * (B_ * N_) + b * N_ + q0 + 2 * j + 1) * H_ + h] =
            make_float2(l2[j][1], cc2[j][1]);
    }
}

__global__ void fin3(const float2* __restrict__ accum, float* __restrict__ out) {
    const int idx = blockIdx.x * 256 + threadIdx.x;   // B*N*H threads
    float L = 0.f, C = 0.f;
    #pragma unroll
    for (int c = 0; c < KC; ++c) {
        float2 a = accum[(size_t)c * (B_ * N_ * H_) + idx];
        L += a.x;
        C += a.y;
    }
    out[idx] = C / L;
}

extern "C" void kernel_launch(void* const* d_in, const int* in_sizes, int n_in,
                              void* d_out, int out_size, void* d_ws, size_t ws_size,
                              hipStream_t stream) {
    const float* word_vecs = (const float*)d_in[0];
    const float* mask      = (const float*)d_in[1];
    const float* Wx_w      = (const float*)d_in[2];
    const float* Wx_b      = (const float*)d_in[3];
    const float* Wa_w      = (const float*)d_in[4];
    const float* Wa_b      = (const float*)d_in[5];
    const float* Ua_w      = (const float*)d_in[6];
    const float* Ua_b      = (const float*)d_in[7];
    float* out = (float*)d_out;

    // workspace layout (16B aligned): ~13.3 MB total
    char* p = (char*)d_ws;
    float*  WxT4  = (float*)p;   p += (size_t)75 * 512 * 4;               // 153.6 KB
    float*  WaT4  = (float*)p;   p += (size_t)32 * 512 * 4;               // 64 KB
    float*  UaT4  = (float*)p;   p += (size_t)32 * 512 * 4;               // 64 KB
    float*  Eta   = (float*)p;   p += (size_t)B_ * N_ * H_ * 4;           // 1 MB
    float4* kv    = (float4*)p;  p += (size_t)B_ * N_ * H_ * 16;          // 4 MB
    float2* accum = (float2*)p;  p += (size_t)KC * B_ * N_ * H_ * 8;      // 8 MB

    pack_all<<<IND_ + 2 * H_, 128, 0, stream>>>(Wx_w, Wa_w, Ua_w, WxT4, WaT4, UaT4);

    prep3<<<(B_ * N_) / RPB, 256, 0, stream>>>(word_vecs, WxT4, Wx_b,
                                               WaT4, Wa_b, UaT4, Ua_b,
                                               mask, Eta, kv);

    dim3 grid(KC, N_ / QQ, B_);
    attn3<<<grid, 128, 0, stream>>>(Eta, kv, accum);

    fin3<<<(B_ * N_ * H_) / 256, 256, 0, stream>>>(accum, out);
}

// Round 6
// 125.758 us; speedup vs baseline: 1.0091x; 1.0091x over previous
//
#include <hip/hip_runtime.h>

#define B_    4
#define N_    512
#define IND_  300
#define H_    128
#define QQ    8          // queries per attention block (even: paired for pk ops)
#define KC    8          // k-chunks. r5 lesson: KC=4 -> 2 waves/SIMD -> attn3
                         // latency-bound (42us, VALUBusy 48%). KC=8 = 4 waves/SIMD
                         // = issue-bound regime. Do not reduce.
#define RPB   4          // rows per prep block (2 per 128-thread group)
#define LOG2E 1.4426950408889634f

typedef float v2f __attribute__((ext_vector_type(2)));

// exp(x) deg-5 Taylor about c=-0.5 for x in [-1,0]; coeffs e^-0.5/k!.
// max err ~1.3e-5 on [-1,0]; all-positive coeffs keep p >= e for e>1 so
// med3(1,e,p) still selects e there.
#define EA0 0.60653065971263342f
#define EA1 0.60653065971263342f
#define EA2 0.30326532985631671f
#define EA3 0.10108844328543890f
#define EA4 0.02527211082135973f
#define EA5 0.00505442216427195f

// ---------------------------------------------------------------------------
// One fused packing kernel: transpose weights to [i/4][t][4] float4 tiles so
// prep's weight loads are coalesced dwordx4. Wa/Ua pre-scaled by log2e so
// prep can use raw exp2.
// ---------------------------------------------------------------------------
__global__ void pack_all(const float* __restrict__ Wx_w,
                         const float* __restrict__ Wa_w,
                         const float* __restrict__ Ua_w,
                         float* __restrict__ WxT4,
                         float* __restrict__ WaT4,
                         float* __restrict__ UaT4) {
    const int blk = blockIdx.x;
    const int t   = threadIdx.x;
    if (blk < IND_) {
        const int i = blk;
        WxT4[(i >> 2) * 512 + t * 4 + (i & 3)] = Wx_w[t * IND_ + i];
    } else if (blk < IND_ + H_) {
        const int i = blk - IND_;
        WaT4[(i >> 2) * 512 + t * 4 + (i & 3)] = Wa_w[t * H_ + i] * LOG2E;
    } else {
        const int i = blk - IND_ - H_;
        UaT4[(i >> 2) * 512 + t * 4 + (i & 3)] = Ua_w[t * H_ + i] * LOG2E;
    }
}

// ---------------------------------------------------------------------------
// Prep, RPB=4 via 256-thread blocks: two 128-thread groups per block, each
// owning 2 rows; both groups share the weight stream (L1 hits). 512 blocks
// = 2 waves/SIMD. (r3: traffic cut beyond RPB=2 is ~neutral — prep3 is at
// its latency/VALU floor; do not touch further.)
// ---------------------------------------------------------------------------
__global__ __launch_bounds__(256) void prep3(
    const float* __restrict__ x,      // [B*N, IND]
    const float* __restrict__ WxT4,   // packed [75][128][4]
    const float* __restrict__ Wx_b,
    const float* __restrict__ WaT4,   // packed [32][128][4], pre-scaled log2e
    const float* __restrict__ Wa_b,
    const float* __restrict__ UaT4,   // packed [32][128][4], pre-scaled log2e
    const float* __restrict__ Ua_b,
    const float* __restrict__ mask,   // [B*N, H]
    float* __restrict__ Eta,          // [B*N, H]
    float4* __restrict__ kv)          // [B*N, H] {Et, M, M*h, 0}
{
    __shared__ __align__(16) float xs[RPB][304];   // 304*4B row stride, 16B aligned
    __shared__ __align__(16) float hs[RPB][H_];

    const int r0 = blockIdx.x * RPB;
    const int t  = threadIdx.x;
    const int g  = t >> 7;            // group 0/1
    const int tt = t & 127;           // h index within group
    const int lr = 2 * g;             // group's first local row

    // all 256 threads cooperatively stage the 4 input rows
    #pragma unroll
    for (int rr = 0; rr < RPB; ++rr) {
        const float* xrow = x + (size_t)(r0 + rr) * IND_;
        for (int i = t; i < IND_; i += 256) xs[rr][i] = xrow[i];
    }
    __syncthreads();

    const float4* w4 = (const float4*)WxT4 + tt;
    const float bx = Wx_b[tt];
    float acc[2];
    acc[0] = bx;
    acc[1] = bx;

    #pragma unroll 5
    for (int i4 = 0; i4 < IND_ / 4; ++i4) {
        float4 w = w4[i4 * 128];      // identical stream in both groups -> L1 hit
        #pragma unroll
        for (int rr = 0; rr < 2; ++rr) {
            float4 xv = *(const float4*)(&xs[lr + rr][4 * i4]);  // lane-broadcast
            acc[rr] = fmaf(w.x, xv.x, acc[rr]);
            acc[rr] = fmaf(w.y, xv.y, acc[rr]);
            acc[rr] = fmaf(w.z, xv.z, acc[rr]);
            acc[rr] = fmaf(w.w, xv.w, acc[rr]);
        }
    }
    float hr[2];
    #pragma unroll
    for (int rr = 0; rr < 2; ++rr) {
        hr[rr] = tanhf(acc[rr]);
        hs[lr + rr][tt] = hr[rr];
    }
    __syncthreads();

    const float4* wa4 = (const float4*)WaT4 + tt;
    const float4* ua4 = (const float4*)UaT4 + tt;
    const float ba = Wa_b[tt] * LOG2E;
    const float bu = Ua_b[tt] * LOG2E;
    float accA[2], accU[2];
    accA[0] = ba; accA[1] = ba;
    accU[0] = bu; accU[1] = bu;

    #pragma unroll 4
    for (int i4 = 0; i4 < H_ / 4; ++i4) {
        float4 wa = wa4[i4 * 128];    // shared stream -> L1 hit for 2nd group
        float4 ua = ua4[i4 * 128];
        #pragma unroll
        for (int rr = 0; rr < 2; ++rr) {
            float4 hv = *(const float4*)(&hs[lr + rr][4 * i4]);
            accA[rr] = fmaf(wa.x, hv.x, accA[rr]);
            accA[rr] = fmaf(wa.y, hv.y, accA[rr]);
            accA[rr] = fmaf(wa.z, hv.z, accA[rr]);
            accA[rr] = fmaf(wa.w, hv.w, accA[rr]);
            accU[rr] = fmaf(ua.x, hv.x, accU[rr]);
            accU[rr] = fmaf(ua.y, hv.y, accU[rr]);
            accU[rr] = fmaf(ua.z, hv.z, accU[rr]);
            accU[rr] = fmaf(ua.w, hv.w, accU[rr]);
        }
    }

    #pragma unroll
    for (int rr = 0; rr < 2; ++rr) {
        const size_t o = (size_t)(r0 + lr + rr) * H_ + tt;
        Eta[o] = __builtin_amdgcn_exp2f(accA[rr]);
        float M = __builtin_amdgcn_exp2f(mask[o] * LOG2E);
        kv[o]  = make_float4(__builtin_amdgcn_exp2f(accU[rr]), M, M * hr[rr], 0.f);
    }
}

// ---------------------------------------------------------------------------
// Attention inner loop, packed-f32 + poly (no transcendentals):
//   e2  = eta2 * Et                        (v_pk_mul_f32)
//   u2  = e2 - 0.5                         (v_pk_add_f32)
//   p   = Taylor5(u2)  ~= exp(e-1)         (5x v_pk_fma_f32, err <= 1.3e-5)
//   p0  = med3(1, e, p)                    (v_med3_f32; == (e>1)?e:exp(e-1))
//   l2  += p0 * M                          (v_pk_fma_f32)
//   cc2 += p0 * (M*hv)                     (v_pk_fma_f32)
// Per 2 scores: 9 pk (18cy) + 2 med3 (4cy) = 22 cyc vs 28 with hw exp2.
// Requires 4 waves/SIMD (KC=8) to stay issue-bound — see r5 lesson above.
// ---------------------------------------------------------------------------
__global__ __launch_bounds__(128) void attn3(
    const float* __restrict__ Eta,    // [B*N, H]
    const float4* __restrict__ kv,    // [B*N, H] {Et, M, M*hv, 0}
    float2* __restrict__ accum)       // [KC, B*N, H] {l, c}
{
    const int c  = blockIdx.x;        // 0..KC-1
    const int qg = blockIdx.y;        // 0..N/QQ-1
    const int b  = blockIdx.z;        // 0..B-1
    const int h  = threadIdx.x;
    const int q0 = qg * QQ;
    const int k0 = c * (N_ / KC);

    v2f eta2[QQ / 2], l2[QQ / 2], cc2[QQ / 2];
    #pragma unroll
    for (int j = 0; j < QQ / 2; ++j) {
        eta2[j][0] = Eta[((size_t)(b * N_ + q0 + 2 * j)) * H_ + h];
        eta2[j][1] = Eta[((size_t)(b * N_ + q0 + 2 * j + 1)) * H_ + h];
        l2[j][0] = 0.f;  l2[j][1] = 0.f;
        cc2[j][0] = 0.f; cc2[j][1] = 0.f;
    }

    // loop-invariant poly constants (VGPR pairs; VOP3P can't take literals)
    v2f cmH; cmH[0] = -0.5f; cmH[1] = -0.5f;
    v2f c5;  c5[0]  = EA5;   c5[1]  = EA5;
    v2f c4;  c4[0]  = EA4;   c4[1]  = EA4;
    v2f c3;  c3[0]  = EA3;   c3[1]  = EA3;
    v2f c2;  c2[0]  = EA2;   c2[1]  = EA2;
    v2f c1;  c1[0]  = EA1;   c1[1]  = EA1;
    v2f c0;  c0[0]  = EA0;   c0[1]  = EA0;

    const float4* kp = kv + ((size_t)(b * N_ + k0)) * H_ + h;

    #pragma unroll 4
    for (int k = 0; k < N_ / KC; ++k) {
        float4 v = kp[(size_t)k * H_];          // {Et, M, M*hv, 0}
        v2f vx; vx[0] = v.x; vx[1] = v.x;
        v2f vy; vy[0] = v.y; vy[1] = v.y;
        v2f vz; vz[0] = v.z; vz[1] = v.z;
        #pragma unroll
        for (int j = 0; j < QQ / 2; ++j) {
            v2f e2, u2, p;
            asm("v_pk_mul_f32 %0, %1, %2"
                : "=v"(e2) : "v"(eta2[j]), "v"(vx));
            asm("v_pk_add_f32 %0, %1, %2"
                : "=v"(u2) : "v"(e2), "v"(cmH));
            asm("v_pk_fma_f32 %0, %1, %2, %3"
                : "=v"(p) : "v"(u2), "v"(c5), "v"(c4));
            asm("v_pk_fma_f32 %0, %1, %2, %3"
                : "=v"(p) : "v"(p), "v"(u2), "v"(c3));
            asm("v_pk_fma_f32 %0, %1, %2, %3"
                : "=v"(p) : "v"(p), "v"(u2), "v"(c2));
            asm("v_pk_fma_f32 %0, %1, %2, %3"
                : "=v"(p) : "v"(p), "v"(u2), "v"(c1));
            asm("v_pk_fma_f32 %0, %1, %2, %3"
                : "=v"(p) : "v"(p), "v"(u2), "v"(c0));
            v2f p0;
            p0[0] = __builtin_amdgcn_fmed3f(1.0f, e2[0], p[0]);
            p0[1] = __builtin_amdgcn_fmed3f(1.0f, e2[1], p[1]);
            asm("v_pk_fma_f32 %0, %1, %2, %0"
                : "+v"(l2[j]) : "v"(p0), "v"(vy));
            asm("v_pk_fma_f32 %0, %1, %2, %0"
                : "+v"(cc2[j]) : "v"(p0), "v"(vz));
        }
    }

    #pragma unroll
    for (int j = 0; j < QQ / 2; ++j) {
        accum[((size_t)c * (B_ * N_) + b * N_ + q0 + 2 * j) * H_ + h] =
            make_float2(l2[j][0], cc2[j][0]);
        accum[((size_t)c * (B_ * N_) + b * N_ + q0 + 2 * j + 1) * H_ + h] =
            make_float2(l2[j][1], cc2[j][1]);
    }
}

__global__ void fin3(const float2* __restrict__ accum, float* __restrict__ out) {
    const int idx = blockIdx.x * 256 + threadIdx.x;   // B*N*H threads
    float L = 0.f, C = 0.f;
    #pragma unroll
    for (int c = 0; c < KC; ++c) {
        float2 a = accum[(size_t)c * (B_ * N_ * H_) + idx];
        L += a.x;
        C += a.y;
    }
    out[idx] = C / L;
}

extern "C" void kernel_launch(void* const* d_in, const int* in_sizes, int n_in,
                              void* d_out, int out_size, void* d_ws, size_t ws_size,
                              hipStream_t stream) {
    const float* word_vecs = (const float*)d_in[0];
    const float* mask      = (const float*)d_in[1];
    const float* Wx_w      = (const float*)d_in[2];
    const float* Wx_b      = (const float*)d_in[3];
    const float* Wa_w      = (const float*)d_in[4];
    const float* Wa_b      = (const float*)d_in[5];
    const float* Ua_w      = (const float*)d_in[6];
    const float* Ua_b      = (const float*)d_in[7];
    float* out = (float*)d_out;

    // workspace layout (16B aligned): ~21.3 MB total
    char* p = (char*)d_ws;
    float*  WxT4  = (float*)p;   p += (size_t)75 * 512 * 4;               // 153.6 KB
    float*  WaT4  = (float*)p;   p += (size_t)32 * 512 * 4;               // 64 KB
    float*  UaT4  = (float*)p;   p += (size_t)32 * 512 * 4;               // 64 KB
    float*  Eta   = (float*)p;   p += (size_t)B_ * N_ * H_ * 4;           // 1 MB
    float4* kv    = (float4*)p;  p += (size_t)B_ * N_ * H_ * 16;          // 4 MB
    float2* accum = (float2*)p;  p += (size_t)KC * B_ * N_ * H_ * 8;      // 16 MB

    pack_all<<<IND_ + 2 * H_, 128, 0, stream>>>(Wx_w, Wa_w, Ua_w, WxT4, WaT4, UaT4);

    prep3<<<(B_ * N_) / RPB, 256, 0, stream>>>(word_vecs, WxT4, Wx_b,
                                               WaT4, Wa_b, UaT4, Ua_b,
                                               mask, Eta, kv);

    dim3 grid(KC, N_ / QQ, B_);
    attn3<<<grid, 128, 0, stream>>>(Eta, kv, accum);

    fin3<<<(B_ * N_ * H_) / 256, 256, 0, stream>>>(accum, out);
}

// Round 7
// 120.300 us; speedup vs baseline: 1.0549x; 1.0454x over previous
//
#include <hip/hip_runtime.h>

#define B_    4
#define N_    512
#define IND_  300
#define H_    128
#define QQ    8          // queries per attention block
#define KC    8          // k-chunks. r5 lesson: KC=4 -> 2 waves/SIMD -> attn3
                         // latency-bound (42us, VALUBusy 48%). KC=8 = 4 waves/SIMD
                         // = issue-bound regime. Do not reduce.
#define RPB   4          // rows per prep block (2 per 128-thread group)
#define LOG2E 1.4426950408889634f

typedef float v2f __attribute__((ext_vector_type(2)));

// r6 lesson: v_exp_f32 runs on the separate transcendental pipe — at 4
// waves/SIMD it is ~free (hidden by other waves' main-pipe issues). The
// deg-5 poly replacement (11 main-pipe issues/pair vs 6) was 5us SLOWER.
// Optimize main-pipe issue count; keep hw exp2.

// ---------------------------------------------------------------------------
// One fused packing kernel: transpose weights to [i/4][t][4] float4 tiles so
// prep's weight loads are coalesced dwordx4. Wa/Ua pre-scaled by log2e so
// prep can use raw exp2.
// ---------------------------------------------------------------------------
__global__ void pack_all(const float* __restrict__ Wx_w,
                         const float* __restrict__ Wa_w,
                         const float* __restrict__ Ua_w,
                         float* __restrict__ WxT4,
                         float* __restrict__ WaT4,
                         float* __restrict__ UaT4) {
    const int blk = blockIdx.x;
    const int t   = threadIdx.x;
    if (blk < IND_) {
        const int i = blk;
        WxT4[(i >> 2) * 512 + t * 4 + (i & 3)] = Wx_w[t * IND_ + i];
    } else if (blk < IND_ + H_) {
        const int i = blk - IND_;
        WaT4[(i >> 2) * 512 + t * 4 + (i & 3)] = Wa_w[t * H_ + i] * LOG2E;
    } else {
        const int i = blk - IND_ - H_;
        UaT4[(i >> 2) * 512 + t * 4 + (i & 3)] = Ua_w[t * H_ + i] * LOG2E;
    }
}

// ---------------------------------------------------------------------------
// Prep, RPB=4 via 256-thread blocks: two 128-thread groups per block, each
// owning 2 rows; both groups share the weight stream (L1 hits). 512 blocks
// = 2 waves/SIMD. (r3: traffic cut beyond RPB=2 is ~neutral — prep3 is at
// its latency/VALU floor; do not touch further.)
//   kv = {Et, M, M*h, Et*log2e}  (.w feeds attn3's exp2 arg directly so the
//                                 fma is independent of e2 — shorter chain)
// ---------------------------------------------------------------------------
__global__ __launch_bounds__(256) void prep3(
    const float* __restrict__ x,      // [B*N, IND]
    const float* __restrict__ WxT4,   // packed [75][128][4]
    const float* __restrict__ Wx_b,
    const float* __restrict__ WaT4,   // packed [32][128][4], pre-scaled log2e
    const float* __restrict__ Wa_b,
    const float* __restrict__ UaT4,   // packed [32][128][4], pre-scaled log2e
    const float* __restrict__ Ua_b,
    const float* __restrict__ mask,   // [B*N, H]
    float* __restrict__ Eta,          // [B*N, H]
    float4* __restrict__ kv)          // [B*N, H] {Et, M, M*h, Et*log2e}
{
    __shared__ __align__(16) float xs[RPB][304];   // 304*4B row stride, 16B aligned
    __shared__ __align__(16) float hs[RPB][H_];

    const int r0 = blockIdx.x * RPB;
    const int t  = threadIdx.x;
    const int g  = t >> 7;            // group 0/1
    const int tt = t & 127;           // h index within group
    const int lr = 2 * g;             // group's first local row

    // all 256 threads cooperatively stage the 4 input rows
    #pragma unroll
    for (int rr = 0; rr < RPB; ++rr) {
        const float* xrow = x + (size_t)(r0 + rr) * IND_;
        for (int i = t; i < IND_; i += 256) xs[rr][i] = xrow[i];
    }
    __syncthreads();

    const float4* w4 = (const float4*)WxT4 + tt;
    const float bx = Wx_b[tt];
    float acc[2];
    acc[0] = bx;
    acc[1] = bx;

    #pragma unroll 5
    for (int i4 = 0; i4 < IND_ / 4; ++i4) {
        float4 w = w4[i4 * 128];      // identical stream in both groups -> L1 hit
        #pragma unroll
        for (int rr = 0; rr < 2; ++rr) {
            float4 xv = *(const float4*)(&xs[lr + rr][4 * i4]);  // lane-broadcast
            acc[rr] = fmaf(w.x, xv.x, acc[rr]);
            acc[rr] = fmaf(w.y, xv.y, acc[rr]);
            acc[rr] = fmaf(w.z, xv.z, acc[rr]);
            acc[rr] = fmaf(w.w, xv.w, acc[rr]);
        }
    }
    float hr[2];
    #pragma unroll
    for (int rr = 0; rr < 2; ++rr) {
        hr[rr] = tanhf(acc[rr]);
        hs[lr + rr][tt] = hr[rr];
    }
    __syncthreads();

    const float4* wa4 = (const float4*)WaT4 + tt;
    const float4* ua4 = (const float4*)UaT4 + tt;
    const float ba = Wa_b[tt] * LOG2E;
    const float bu = Ua_b[tt] * LOG2E;
    float accA[2], accU[2];
    accA[0] = ba; accA[1] = ba;
    accU[0] = bu; accU[1] = bu;

    #pragma unroll 4
    for (int i4 = 0; i4 < H_ / 4; ++i4) {
        float4 wa = wa4[i4 * 128];    // shared stream -> L1 hit for 2nd group
        float4 ua = ua4[i4 * 128];
        #pragma unroll
        for (int rr = 0; rr < 2; ++rr) {
            float4 hv = *(const float4*)(&hs[lr + rr][4 * i4]);
            accA[rr] = fmaf(wa.x, hv.x, accA[rr]);
            accA[rr] = fmaf(wa.y, hv.y, accA[rr]);
            accA[rr] = fmaf(wa.z, hv.z, accA[rr]);
            accA[rr] = fmaf(wa.w, hv.w, accA[rr]);
            accU[rr] = fmaf(ua.x, hv.x, accU[rr]);
            accU[rr] = fmaf(ua.y, hv.y, accU[rr]);
            accU[rr] = fmaf(ua.z, hv.z, accU[rr]);
            accU[rr] = fmaf(ua.w, hv.w, accU[rr]);
        }
    }

    #pragma unroll
    for (int rr = 0; rr < 2; ++rr) {
        const size_t o = (size_t)(r0 + lr + rr) * H_ + tt;
        Eta[o] = __builtin_amdgcn_exp2f(accA[rr]);
        float M  = __builtin_amdgcn_exp2f(mask[o] * LOG2E);
        float Et = __builtin_amdgcn_exp2f(accU[rr]);
        kv[o]  = make_float4(Et, M, M * hr[rr], Et * LOG2E);
    }
}

// ---------------------------------------------------------------------------
// Attention inner loop, k-paired packed-f32 + hw exp2.
// Each v2f lane-pair holds {k, k+1} for ONE query:
//   e2 = etaB[j] * {Et[k],Et[k+1]}        (v_pk_mul_f32)
//   a2 = etaB[j] * {EtL[k],EtL[k+1]} - L2E (v_pk_fma_f32, indep of e2)
//   pn = exp2(a2)                          (2x v_exp_f32, trans pipe ~free)
//   p0 = med3(1, e2, pn)                   (2x v_med3_f32)
//   l2  += p0 * {M}   ; cc2 += p0 * {M*hv} (2x v_pk_fma_f32)
// Pair-builds {va.x,vb.x}... amortize over all 8 q's (0.75 iss/pair vs 1.5
// for q-pairing); etaB broadcasts hoisted out of the k-loop entirely.
// Halves accumulate even/odd k; horizontal add at the end.
// ---------------------------------------------------------------------------
__global__ __launch_bounds__(128) void attn3(
    const float* __restrict__ Eta,    // [B*N, H]
    const float4* __restrict__ kv,    // [B*N, H] {Et, M, M*hv, Et*log2e}
    float2* __restrict__ accum)       // [KC, B*N, H] {l, c}
{
    const int c  = blockIdx.x;        // 0..KC-1
    const int qg = blockIdx.y;        // 0..N/QQ-1
    const int b  = blockIdx.z;        // 0..B-1
    const int h  = threadIdx.x;
    const int q0 = qg * QQ;
    const int k0 = c * (N_ / KC);

    v2f etaB[QQ], l2[QQ], cc2[QQ];
    #pragma unroll
    for (int j = 0; j < QQ; ++j) {
        float e = Eta[((size_t)(b * N_ + q0 + j)) * H_ + h];
        etaB[j][0] = e;  etaB[j][1] = e;
        l2[j][0] = 0.f;  l2[j][1] = 0.f;
        cc2[j][0] = 0.f; cc2[j][1] = 0.f;
    }

    v2f cNL2; cNL2[0] = -LOG2E; cNL2[1] = -LOG2E;   // VOP3P can't take literals

    const float4* kp = kv + ((size_t)(b * N_ + k0)) * H_ + h;

    #pragma unroll 2
    for (int k2 = 0; k2 < N_ / KC / 2; ++k2) {
        float4 va = kp[(size_t)(2 * k2) * H_];
        float4 vb = kp[(size_t)(2 * k2 + 1) * H_];
        v2f vx; vx[0] = va.x; vx[1] = vb.x;   // {Et}
        v2f vy; vy[0] = va.y; vy[1] = vb.y;   // {M}
        v2f vz; vz[0] = va.z; vz[1] = vb.z;   // {M*hv}
        v2f vw; vw[0] = va.w; vw[1] = vb.w;   // {Et*log2e}
        #pragma unroll
        for (int j = 0; j < QQ; ++j) {
            v2f e2, a2;
            asm("v_pk_mul_f32 %0, %1, %2"
                : "=v"(e2) : "v"(etaB[j]), "v"(vx));
            asm("v_pk_fma_f32 %0, %1, %2, %3"
                : "=v"(a2) : "v"(etaB[j]), "v"(vw), "v"(cNL2));
            float pn0 = __builtin_amdgcn_exp2f(a2[0]);
            float pn1 = __builtin_amdgcn_exp2f(a2[1]);
            v2f p0;
            p0[0] = __builtin_amdgcn_fmed3f(1.0f, e2[0], pn0);
            p0[1] = __builtin_amdgcn_fmed3f(1.0f, e2[1], pn1);
            asm("v_pk_fma_f32 %0, %1, %2, %0"
                : "+v"(l2[j]) : "v"(p0), "v"(vy));
            asm("v_pk_fma_f32 %0, %1, %2, %0"
                : "+v"(cc2[j]) : "v"(p0), "v"(vz));
        }
    }

    #pragma unroll
    for (int j = 0; j < QQ; ++j) {
        accum[((size_t)c * (B_ * N_) + b * N_ + q0 + j) * H_ + h] =
            make_float2(l2[j][0] + l2[j][1], cc2[j][0] + cc2[j][1]);
    }
}

__global__ void fin3(const float2* __restrict__ accum, float* __restrict__ out) {
    const int idx = blockIdx.x * 256 + threadIdx.x;   // B*N*H threads
    float L = 0.f, C = 0.f;
    #pragma unroll
    for (int c = 0; c < KC; ++c) {
        float2 a = accum[(size_t)c * (B_ * N_ * H_) + idx];
        L += a.x;
        C += a.y;
    }
    out[idx] = C / L;
}

extern "C" void kernel_launch(void* const* d_in, const int* in_sizes, int n_in,
                              void* d_out, int out_size, void* d_ws, size_t ws_size,
                              hipStream_t stream) {
    const float* word_vecs = (const float*)d_in[0];
    const float* mask      = (const float*)d_in[1];
    const float* Wx_w      = (const float*)d_in[2];
    const float* Wx_b      = (const float*)d_in[3];
    const float* Wa_w      = (const float*)d_in[4];
    const float* Wa_b      = (const float*)d_in[5];
    const float* Ua_w      = (const float*)d_in[6];
    const float* Ua_b      = (const float*)d_in[7];
    float* out = (float*)d_out;

    // workspace layout (16B aligned): ~21.3 MB total
    char* p = (char*)d_ws;
    float*  WxT4  = (float*)p;   p += (size_t)75 * 512 * 4;               // 153.6 KB
    float*  WaT4  = (float*)p;   p += (size_t)32 * 512 * 4;               // 64 KB
    float*  UaT4  = (float*)p;   p += (size_t)32 * 512 * 4;               // 64 KB
    float*  Eta   = (float*)p;   p += (size_t)B_ * N_ * H_ * 4;           // 1 MB
    float4* kv    = (float4*)p;  p += (size_t)B_ * N_ * H_ * 16;          // 4 MB
    float2* accum = (float2*)p;  p += (size_t)KC * B_ * N_ * H_ * 8;      // 16 MB

    pack_all<<<IND_ + 2 * H_, 128, 0, stream>>>(Wx_w, Wa_w, Ua_w, WxT4, WaT4, UaT4);

    prep3<<<(B_ * N_) / RPB, 256, 0, stream>>>(word_vecs, WxT4, Wx_b,
                                               WaT4, Wa_b, UaT4, Ua_b,
                                               mask, Eta, kv);

    dim3 grid(KC, N_ / QQ, B_);
    attn3<<<grid, 128, 0, stream>>>(Eta, kv, accum);

    fin3<<<(B_ * N_ * H_) / 256, 256, 0, stream>>>(accum, out);
}

// Round 9
// 119.883 us; speedup vs baseline: 1.0586x; 1.0035x over previous
//
#include <hip/hip_runtime.h>

#define B_    4
#define N_    512
#define IND_  300
#define H_    128
#define QQ    8          // queries per attention block
#define KC    8          // k-chunks. r5 lesson: KC=4 -> 2 waves/SIMD -> attn3
                         // latency-bound (42us, VALUBusy 48%). KC=8 = 4 waves/SIMD
                         // = issue-bound regime. Do not reduce.
#define RPB   4          // rows per prep block (2 per 128-thread group)
#define LOG2E 1.4426950408889634f

typedef float v2f __attribute__((ext_vector_type(2)));
struct __align__(16) kvp2 { v2f a, b; };   // 16B record = 2 pk-ready operand pairs

// r6 lesson: v_exp_f32 runs on the separate transcendental pipe — at 4
// waves/SIMD it is ~free (hidden by other waves' main-pipe issues). Keep
// hw exp2; minimize main-pipe issues.
// r8 lesson: cross-block last-block-finalize via threadfence+atomic counter
// is NOT safe on MI355X (per-XCD L2 non-coherence: plain loads of other
// blocks' stores can be stale even after device fences) — absmax 4e-2.
// Keep the separate fin3 dispatch.

// ---------------------------------------------------------------------------
// Packing kernel: transpose weights to [i/4][t][4] float4 tiles (coalesced
// dwordx4 in prep3); Wa/Ua pre-scaled by log2e.
// ---------------------------------------------------------------------------
__global__ void pack_all(const float* __restrict__ Wx_w,
                         const float* __restrict__ Wa_w,
                         const float* __restrict__ Ua_w,
                         float* __restrict__ WxT4,
                         float* __restrict__ WaT4,
                         float* __restrict__ UaT4) {
    const int blk = blockIdx.x;
    const int t   = threadIdx.x;
    if (blk < IND_) {
        const int i = blk;
        WxT4[(i >> 2) * 512 + t * 4 + (i & 3)] = Wx_w[t * IND_ + i];
    } else if (blk < IND_ + H_) {
        const int i = blk - IND_;
        WaT4[(i >> 2) * 512 + t * 4 + (i & 3)] = Wa_w[t * H_ + i] * LOG2E;
    } else {
        const int i = blk - IND_ - H_;
        UaT4[(i >> 2) * 512 + t * 4 + (i & 3)] = Ua_w[t * H_ + i] * LOG2E;
    }
}

// ---------------------------------------------------------------------------
// Prep, RPB=4 via 256-thread blocks: two 128-thread groups per block, each
// owning 2 CONSECUTIVE rows (= one k-pair); both groups share the weight
// stream (L1 hits). 512 blocks = 2 waves/SIMD. (r3: traffic cut beyond
// RPB=2 is ~neutral — prep3 at latency/VALU floor; do not touch.)
// Outputs (pair-SoA, r8):
//   Eta  [B*N, H]                        exp(ta) per q,h
//   kvpA [B*N/2, H] {Et0,Et1, M0,M1}     adjacent-reg pk operands
//   kvpB [B*N/2, H] {Mh0,Mh1, EtL0,EtL1} (EtL = Et*log2e -> exp2 arg fma
//                                          independent of e2)
// ---------------------------------------------------------------------------
__global__ __launch_bounds__(256) void prep3(
    const float* __restrict__ x,      // [B*N, IND]
    const float* __restrict__ WxT4,   // packed [75][128][4]
    const float* __restrict__ Wx_b,
    const float* __restrict__ WaT4,   // packed [32][128][4], pre-scaled log2e
    const float* __restrict__ Wa_b,
    const float* __restrict__ UaT4,   // packed [32][128][4], pre-scaled log2e
    const float* __restrict__ Ua_b,
    const float* __restrict__ mask,   // [B*N, H]
    float* __restrict__ Eta,          // [B*N, H]
    kvp2* __restrict__ kvpA,          // [B*N/2, H]
    kvp2* __restrict__ kvpB)          // [B*N/2, H]
{
    __shared__ __align__(16) float xs[RPB][304];   // 304*4B row stride, 16B aligned
    __shared__ __align__(16) float hs[RPB][H_];

    const int r0 = blockIdx.x * RPB;
    const int t  = threadIdx.x;
    const int g  = t >> 7;            // group 0/1
    const int tt = t & 127;           // h index within group
    const int lr = 2 * g;             // group's first local row

    // all 256 threads cooperatively stage the 4 input rows
    #pragma unroll
    for (int rr = 0; rr < RPB; ++rr) {
        const float* xrow = x + (size_t)(r0 + rr) * IND_;
        for (int i = t; i < IND_; i += 256) xs[rr][i] = xrow[i];
    }
    __syncthreads();

    const float4* w4 = (const float4*)WxT4 + tt;
    const float bx = Wx_b[tt];
    float acc[2];
    acc[0] = bx;
    acc[1] = bx;

    #pragma unroll 5
    for (int i4 = 0; i4 < IND_ / 4; ++i4) {
        float4 w = w4[i4 * 128];      // identical stream in both groups -> L1 hit
        #pragma unroll
        for (int rr = 0; rr < 2; ++rr) {
            float4 xv = *(const float4*)(&xs[lr + rr][4 * i4]);  // lane-broadcast
            acc[rr] = fmaf(w.x, xv.x, acc[rr]);
            acc[rr] = fmaf(w.y, xv.y, acc[rr]);
            acc[rr] = fmaf(w.z, xv.z, acc[rr]);
            acc[rr] = fmaf(w.w, xv.w, acc[rr]);
        }
    }
    float hr[2];
    #pragma unroll
    for (int rr = 0; rr < 2; ++rr) {
        hr[rr] = tanhf(acc[rr]);
        hs[lr + rr][tt] = hr[rr];
    }
    __syncthreads();

    const float4* wa4 = (const float4*)WaT4 + tt;
    const float4* ua4 = (const float4*)UaT4 + tt;
    const float ba = Wa_b[tt] * LOG2E;
    const float bu = Ua_b[tt] * LOG2E;
    float accA[2], accU[2];
    accA[0] = ba; accA[1] = ba;
    accU[0] = bu; accU[1] = bu;

    #pragma unroll 4
    for (int i4 = 0; i4 < H_ / 4; ++i4) {
        float4 wa = wa4[i4 * 128];    // shared stream -> L1 hit for 2nd group
        float4 ua = ua4[i4 * 128];
        #pragma unroll
        for (int rr = 0; rr < 2; ++rr) {
            float4 hv = *(const float4*)(&hs[lr + rr][4 * i4]);
            accA[rr] = fmaf(wa.x, hv.x, accA[rr]);
            accA[rr] = fmaf(wa.y, hv.y, accA[rr]);
            accA[rr] = fmaf(wa.z, hv.z, accA[rr]);
            accA[rr] = fmaf(wa.w, hv.w, accA[rr]);
            accU[rr] = fmaf(ua.x, hv.x, accU[rr]);
            accU[rr] = fmaf(ua.y, hv.y, accU[rr]);
            accU[rr] = fmaf(ua.z, hv.z, accU[rr]);
            accU[rr] = fmaf(ua.w, hv.w, accU[rr]);
        }
    }

    float Et[2], Mm[2];
    #pragma unroll
    for (int rr = 0; rr < 2; ++rr) {
        const size_t o = (size_t)(r0 + lr + rr) * H_ + tt;
        Eta[o]  = __builtin_amdgcn_exp2f(accA[rr]);
        Mm[rr]  = __builtin_amdgcn_exp2f(mask[o] * LOG2E);
        Et[rr]  = __builtin_amdgcn_exp2f(accU[rr]);
    }
    // this thread owns BOTH rows of pair p — write pair-SoA records directly
    const size_t p = (size_t)(r0 + lr) / 2 * H_ + tt;
    kvp2 A, Bk;
    A.a[0]  = Et[0];          A.a[1]  = Et[1];
    A.b[0]  = Mm[0];          A.b[1]  = Mm[1];
    Bk.a[0] = Mm[0] * hr[0];  Bk.a[1] = Mm[1] * hr[1];
    Bk.b[0] = Et[0] * LOG2E;  Bk.b[1] = Et[1] * LOG2E;
    kvpA[p] = A;
    kvpB[p] = Bk;
}

// ---------------------------------------------------------------------------
// Attention, k-paired packed-f32 + hw exp2 (r7 structure, r8 layout).
// Per k-pair record the fields load directly as adjacent-reg pk operands —
// zero broadcast movs:
//   e2 = etaB[j]*{Et}          (v_pk_mul_f32)
//   a2 = etaB[j]*{EtL} - L2E   (v_pk_fma_f32, indep of e2)
//   pn = exp2(a2)              (2x v_exp_f32, trans pipe ~free)
//   p0 = med3(1, e2, pn)       (2x v_med3_f32)
//   l2 += p0*{M}; cc2 += p0*{M*hv}  (2x v_pk_fma_f32)
// Halves accumulate even/odd k; horizontal add at the end.
// ---------------------------------------------------------------------------
__global__ __launch_bounds__(128) void attn3(
    const float* __restrict__ Eta,    // [B*N, H]
    const kvp2* __restrict__ kvpA,    // [B*N/2, H]
    const kvp2* __restrict__ kvpB,    // [B*N/2, H]
    float2* __restrict__ accum)       // [KC, B*N, H] {l, c}
{
    const int c  = blockIdx.x;        // 0..KC-1
    const int qg = blockIdx.y;        // 0..N/QQ-1
    const int b  = blockIdx.z;        // 0..B-1
    const int h  = threadIdx.x;
    const int q0 = qg * QQ;
    const int k0 = c * (N_ / KC);

    v2f etaB[QQ], l2[QQ], cc2[QQ];
    #pragma unroll
    for (int j = 0; j < QQ; ++j) {
        float e = Eta[((size_t)(b * N_ + q0 + j)) * H_ + h];
        etaB[j][0] = e;  etaB[j][1] = e;
        l2[j][0] = 0.f;  l2[j][1] = 0.f;
        cc2[j][0] = 0.f; cc2[j][1] = 0.f;
    }

    v2f cNL2; cNL2[0] = -LOG2E; cNL2[1] = -LOG2E;   // VOP3P can't take literals

    const kvp2* kpA = kvpA + ((size_t)(b * N_ + k0) >> 1) * H_ + h;
    const kvp2* kpB = kvpB + ((size_t)(b * N_ + k0) >> 1) * H_ + h;

    #pragma unroll 2
    for (int k2 = 0; k2 < N_ / KC / 2; ++k2) {
        kvp2 pa = kpA[(size_t)k2 * H_];   // {Et0,Et1, M0,M1}
        kvp2 pb = kpB[(size_t)k2 * H_];   // {Mh0,Mh1, EtL0,EtL1}
        #pragma unroll
        for (int j = 0; j < QQ; ++j) {
            v2f e2, a2;
            asm("v_pk_mul_f32 %0, %1, %2"
                : "=v"(e2) : "v"(etaB[j]), "v"(pa.a));
            asm("v_pk_fma_f32 %0, %1, %2, %3"
                : "=v"(a2) : "v"(etaB[j]), "v"(pb.b), "v"(cNL2));
            float pn0 = __builtin_amdgcn_exp2f(a2[0]);
            float pn1 = __builtin_amdgcn_exp2f(a2[1]);
            v2f p0;
            p0[0] = __builtin_amdgcn_fmed3f(1.0f, e2[0], pn0);
            p0[1] = __builtin_amdgcn_fmed3f(1.0f, e2[1], pn1);
            asm("v_pk_fma_f32 %0, %1, %2, %0"
                : "+v"(l2[j]) : "v"(p0), "v"(pa.b));
            asm("v_pk_fma_f32 %0, %1, %2, %0"
                : "+v"(cc2[j]) : "v"(p0), "v"(pb.a));
        }
    }

    #pragma unroll
    for (int j = 0; j < QQ; ++j) {
        accum[((size_t)c * (B_ * N_) + b * N_ + q0 + j) * H_ + h] =
            make_float2(l2[j][0] + l2[j][1], cc2[j][0] + cc2[j][1]);
    }
}

__global__ void fin3(const float2* __restrict__ accum, float* __restrict__ out) {
    const int idx = blockIdx.x * 256 + threadIdx.x;   // B*N*H threads
    float L = 0.f, C = 0.f;
    #pragma unroll
    for (int c = 0; c < KC; ++c) {
        float2 a = accum[(size_t)c * (B_ * N_ * H_) + idx];
        L += a.x;
        C += a.y;
    }
    out[idx] = C / L;
}

extern "C" void kernel_launch(void* const* d_in, const int* in_sizes, int n_in,
                              void* d_out, int out_size, void* d_ws, size_t ws_size,
                              hipStream_t stream) {
    const float* word_vecs = (const float*)d_in[0];
    const float* mask      = (const float*)d_in[1];
    const float* Wx_w      = (const float*)d_in[2];
    const float* Wx_b      = (const float*)d_in[3];
    const float* Wa_w      = (const float*)d_in[4];
    const float* Wa_b      = (const float*)d_in[5];
    const float* Ua_w      = (const float*)d_in[6];
    const float* Ua_b      = (const float*)d_in[7];
    float* out = (float*)d_out;

    // workspace layout (16B aligned): ~21.3 MB total
    char* p = (char*)d_ws;
    float*  WxT4  = (float*)p;   p += (size_t)75 * 512 * 4;               // 153.6 KB
    float*  WaT4  = (float*)p;   p += (size_t)32 * 512 * 4;               // 64 KB
    float*  UaT4  = (float*)p;   p += (size_t)32 * 512 * 4;               // 64 KB
    float*  Eta   = (float*)p;   p += (size_t)B_ * N_ * H_ * 4;           // 1 MB
    kvp2*   kvpA  = (kvp2*)p;    p += (size_t)(B_ * N_ / 2) * H_ * 16;    // 2 MB
    kvp2*   kvpB  = (kvp2*)p;    p += (size_t)(B_ * N_ / 2) * H_ * 16;    // 2 MB
    float2* accum = (float2*)p;  p += (size_t)KC * B_ * N_ * H_ * 8;      // 16 MB

    pack_all<<<IND_ + 2 * H_, 128, 0, stream>>>(Wx_w, Wa_w, Ua_w, WxT4, WaT4, UaT4);

    prep3<<<(B_ * N_) / RPB, 256, 0, stream>>>(word_vecs, WxT4, Wx_b,
                                               WaT4, Wa_b, UaT4, Ua_b,
                                               mask, Eta, kvpA, kvpB);

    dim3 grid(KC, N_ / QQ, B_);
    attn3<<<grid, 128, 0, stream>>>(Eta, kvpA, kvpB, accum);

    fin3<<<(B_ * N_ * H_) / 256, 256, 0, stream>>>(accum, out);
}